// Round 1
// baseline (364.613 us; speedup 1.0000x reference)
//
#include <hip/hip_runtime.h>
#include <math.h>

#define T_TOK 8192
#define HDIM 4096
#define NSLOT 128
#define KRET 4
#define TOPK 2048
#define ALPHA 0.1f

// ---------------- Kernel 1: per-token importance ----------------
__global__ __launch_bounds__(256) void importance_kernel(
    const float* __restrict__ h, const float* __restrict__ attn,
    const float* __restrict__ W, const float* __restrict__ b,
    float* __restrict__ imp)
{
    const int t = blockIdx.x;
    const float4* hv = reinterpret_cast<const float4*>(h + (size_t)t * HDIM);
    const float4* Wv = reinterpret_cast<const float4*>(W);
    float sumsq = 0.f, dot = 0.f;
    for (int i = threadIdx.x; i < HDIM / 4; i += 256) {
        float4 x = hv[i];
        float4 w = Wv[i];
        sumsq += x.x * x.x + x.y * x.y + x.z * x.z + x.w * x.w;
        dot   += x.x * w.x + x.y * w.y + x.z * w.z + x.w * w.w;
    }
    // wave (64-lane) reduction
    #pragma unroll
    for (int off = 32; off > 0; off >>= 1) {
        sumsq += __shfl_down(sumsq, off);
        dot   += __shfl_down(dot, off);
    }
    __shared__ float s_sq[4], s_dot[4];
    const int lane = threadIdx.x & 63, wid = threadIdx.x >> 6;
    if (lane == 0) { s_sq[wid] = sumsq; s_dot[wid] = dot; }
    __syncthreads();
    if (threadIdx.x == 0) {
        float sq = s_sq[0] + s_sq[1] + s_sq[2] + s_sq[3];
        float dt = s_dot[0] + s_dot[1] + s_dot[2] + s_dot[3];
        float mag = sqrtf(sq);
        float ent = 0.f;
        #pragma unroll
        for (int k = 0; k < KRET; k++) {
            float a = attn[t * KRET + k];
            ent -= a * logf(a + 1e-8f);
        }
        float surprise = ent / logf(4.0f);
        float score = dt + b[0];
        float sig = 1.0f / (1.0f + expf(-score));
        imp[t] = mag * (1.0f + surprise) + sig;
    }
}

// ---------------- Kernel 2: exact top-K selection via rank count ----------------
__global__ __launch_bounds__(256) void select_kernel(
    const float* __restrict__ imp, int* __restrict__ flags)
{
    const int t = blockIdx.x * 256 + threadIdx.x;
    const float mine = imp[t];
    __shared__ float tile[2048];
    int rank = 0;
    for (int base = 0; base < T_TOK; base += 2048) {
        for (int i = threadIdx.x; i < 2048; i += 256) tile[i] = imp[base + i];
        __syncthreads();
        #pragma unroll 8
        for (int i = 0; i < 2048; i++) {
            float v = tile[i];
            int s = base + i;
            // jax.lax.top_k tie-break: higher value first, then lower index
            rank += (v > mine) || (v == mine && s < t);
        }
        __syncthreads();
    }
    flags[t] = (rank < TOPK) ? 1 : 0;
}

// ---------------- Kernel 3: ordered compaction + deduped slot counts ----------------
__global__ __launch_bounds__(1024) void compact_kernel(
    const int* __restrict__ flags, const int* __restrict__ si,
    int* __restrict__ sel_tok, unsigned int* __restrict__ packed,
    int* __restrict__ counts)
{
    __shared__ int part[1024];
    __shared__ int s_counts[NSLOT];
    const int tid = threadIdx.x;
    if (tid < NSLOT) s_counts[tid] = 0;
    const int base = tid * 8;
    int f[8];
    int local = 0;
    #pragma unroll
    for (int j = 0; j < 8; j++) { f[j] = flags[base + j]; local += f[j]; }
    part[tid] = local;
    __syncthreads();
    // Hillis-Steele inclusive scan over 1024 partials
    for (int off = 1; off < 1024; off <<= 1) {
        int v = part[tid];
        int add = (tid >= off) ? part[tid - off] : 0;
        __syncthreads();
        part[tid] = v + add;
        __syncthreads();
    }
    int pos = part[tid] - local;  // exclusive prefix
    #pragma unroll
    for (int j = 0; j < 8; j++) {
        int t = base + j;
        if (f[j]) {
            int s0 = si[t * 4 + 0], s1 = si[t * 4 + 1];
            int s2 = si[t * 4 + 2], s3 = si[t * 4 + 3];
            sel_tok[pos] = t;
            packed[pos] = (unsigned)s0 | ((unsigned)s1 << 8) |
                          ((unsigned)s2 << 16) | ((unsigned)s3 << 24);
            pos++;
            // dedupe within the token (membership is binary)
            atomicAdd(&s_counts[s0], 1);
            if (s1 != s0) atomicAdd(&s_counts[s1], 1);
            if (s2 != s0 && s2 != s1) atomicAdd(&s_counts[s2], 1);
            if (s3 != s0 && s3 != s1 && s3 != s2) atomicAdd(&s_counts[s3], 1);
        }
    }
    __syncthreads();
    if (tid < NSLOT) counts[tid] = s_counts[tid];
}

// ---------------- Kernel 4: segment-mean + EMA + write full output ----------------
__global__ __launch_bounds__(256) void update_kernel(
    const float* __restrict__ h, const float* __restrict__ mem,
    const int* __restrict__ sel_tok, const unsigned int* __restrict__ packed,
    const int* __restrict__ counts, float* __restrict__ out)
{
    const int slot = blockIdx.x >> 2;   // 128 slots
    const int chunk = blockIdx.x & 3;   // 4 chunks of 1024 floats
    __shared__ unsigned int s_packed[TOPK];
    __shared__ int s_tok[TOPK];
    for (int i = threadIdx.x; i < TOPK; i += 256) {
        s_packed[i] = packed[i];
        s_tok[i] = sel_tok[i];
    }
    __syncthreads();
    const unsigned pat = (unsigned)slot * 0x01010101u;
    float4 acc = make_float4(0.f, 0.f, 0.f, 0.f);
    const int dbase = chunk * 1024 + threadIdx.x * 4;
    for (int i = 0; i < TOPK; i++) {
        unsigned p = s_packed[i] ^ pat;
        // any byte == 0  <=>  slot appears in this token's retrieved set
        bool member = ((p - 0x01010101u) & ~p & 0x80808080u) != 0u;
        if (member) {
            const float4 x = *reinterpret_cast<const float4*>(
                h + (size_t)s_tok[i] * HDIM + dbase);
            acc.x += x.x; acc.y += x.y; acc.z += x.z; acc.w += x.w;
        }
    }
    const int cnt = counts[slot];
    const size_t o = (size_t)slot * HDIM + dbase;
    float4 cur = *reinterpret_cast<const float4*>(mem + o);
    float4 r;
    if (cnt > 0) {
        float inv = 1.0f / (float)cnt;
        r.x = ALPHA * (acc.x * inv) + (1.f - ALPHA) * cur.x;
        r.y = ALPHA * (acc.y * inv) + (1.f - ALPHA) * cur.y;
        r.z = ALPHA * (acc.z * inv) + (1.f - ALPHA) * cur.z;
        r.w = ALPHA * (acc.w * inv) + (1.f - ALPHA) * cur.w;
    } else {
        r = cur;
    }
    *reinterpret_cast<float4*>(out + o) = r;
}

extern "C" void kernel_launch(void* const* d_in, const int* in_sizes, int n_in,
                              void* d_out, int out_size, void* d_ws, size_t ws_size,
                              hipStream_t stream) {
    const float* h    = (const float*)d_in[0];  // [8192, 4096]
    const float* attn = (const float*)d_in[1];  // [8192, 4]
    const int*   si   = (const int*)d_in[2];    // [8192, 4]
    const float* mem  = (const float*)d_in[3];  // [1, 128, 4096]
    const float* W    = (const float*)d_in[4];  // [1, 4096]
    const float* b    = (const float*)d_in[5];  // [1]
    float* out = (float*)d_out;                 // [1, 128, 4096]

    char* ws = (char*)d_ws;
    float*        imp     = (float*)(ws);                 // 8192 f32
    int*          flags   = (int*)(ws + 32768);           // 8192 i32
    int*          sel_tok = (int*)(ws + 65536);           // 2048 i32
    unsigned int* packed  = (unsigned int*)(ws + 73728);  // 2048 u32
    int*          counts  = (int*)(ws + 81920);           // 128 i32

    importance_kernel<<<T_TOK, 256, 0, stream>>>(h, attn, W, b, imp);
    select_kernel<<<T_TOK / 256, 256, 0, stream>>>(imp, flags);
    compact_kernel<<<1, 1024, 0, stream>>>(flags, si, sel_tok, packed, counts);
    update_kernel<<<NSLOT * 4, 256, 0, stream>>>(h, mem, sel_tok, packed, counts, out);
}

// Round 2
// 180.313 us; speedup vs baseline: 2.0221x; 2.0221x over previous
//
#include <hip/hip_runtime.h>
#include <math.h>

#define T_TOK 8192
#define HDIM 4096
#define NSLOT 128
#define KRET 4
#define TOPK 2048
#define ALPHA 0.1f

// ---------------- Kernel 1: per-token importance (+ zero rank) ----------------
__global__ __launch_bounds__(256) void importance_kernel(
    const float* __restrict__ h, const float* __restrict__ attn,
    const float* __restrict__ W, const float* __restrict__ b,
    float* __restrict__ imp, int* __restrict__ rank)
{
    const int t = blockIdx.x;
    const float4* hv = reinterpret_cast<const float4*>(h + (size_t)t * HDIM);
    const float4* Wv = reinterpret_cast<const float4*>(W);
    float sumsq = 0.f, dot = 0.f;
    for (int i = threadIdx.x; i < HDIM / 4; i += 256) {
        float4 x = hv[i];
        float4 w = Wv[i];
        sumsq += x.x * x.x + x.y * x.y + x.z * x.z + x.w * x.w;
        dot   += x.x * w.x + x.y * w.y + x.z * w.z + x.w * w.w;
    }
    #pragma unroll
    for (int off = 32; off > 0; off >>= 1) {
        sumsq += __shfl_down(sumsq, off);
        dot   += __shfl_down(dot, off);
    }
    __shared__ float s_sq[4], s_dot[4];
    const int lane = threadIdx.x & 63, wid = threadIdx.x >> 6;
    if (lane == 0) { s_sq[wid] = sumsq; s_dot[wid] = dot; }
    __syncthreads();
    if (threadIdx.x == 0) {
        float sq = s_sq[0] + s_sq[1] + s_sq[2] + s_sq[3];
        float dt = s_dot[0] + s_dot[1] + s_dot[2] + s_dot[3];
        float mag = sqrtf(sq);
        float ent = 0.f;
        #pragma unroll
        for (int k = 0; k < KRET; k++) {
            float a = attn[t * KRET + k];
            ent -= a * logf(a + 1e-8f);
        }
        float surprise = ent / logf(4.0f);
        float score = dt + b[0];
        float sig = 1.0f / (1.0f + expf(-score));
        imp[t] = mag * (1.0f + surprise) + sig;
        rank[t] = 0;  // zero for rank_kernel (stream-ordered, replay-safe)
    }
}

// ---------------- Kernel 2: partial rank count, 2-D grid ----------------
// grid = 32 candidate-blocks x 32 slice-blocks; each thread owns one
// candidate and compares against a 256-value LDS tile (broadcast reads).
__global__ __launch_bounds__(256) void rank_kernel(
    const float* __restrict__ imp, int* __restrict__ rank)
{
    const int cb = blockIdx.x & 31;   // candidate block
    const int sl = blockIdx.x >> 5;   // compare slice
    __shared__ float tile[256];
    const int base = sl * 256;
    tile[threadIdx.x] = imp[base + threadIdx.x];
    __syncthreads();
    const int t = cb * 256 + threadIdx.x;
    const float mine = imp[t];
    int r = 0;
    #pragma unroll 8
    for (int i = 0; i < 256; i++) {
        float v = tile[i];
        int s = base + i;
        // jax.lax.top_k tie-break: higher value first, then lower index
        r += (v > mine) || (v == mine && s < t);
    }
    if (r) atomicAdd(&rank[t], r);
}

// ---------------- Kernel 3: ordered compaction + deduped slot counts ----------------
__global__ __launch_bounds__(1024) void compact_kernel(
    const int* __restrict__ rank, const int* __restrict__ si,
    int* __restrict__ sel_tok, unsigned int* __restrict__ packed,
    int* __restrict__ counts)
{
    __shared__ int part[1024];
    __shared__ int s_counts[NSLOT];
    const int tid = threadIdx.x;
    if (tid < NSLOT) s_counts[tid] = 0;
    const int base = tid * 8;
    int f[8];
    int local = 0;
    #pragma unroll
    for (int j = 0; j < 8; j++) {
        f[j] = (rank[base + j] < TOPK) ? 1 : 0;
        local += f[j];
    }
    part[tid] = local;
    __syncthreads();
    // Hillis-Steele inclusive scan over 1024 partials
    for (int off = 1; off < 1024; off <<= 1) {
        int v = part[tid];
        int add = (tid >= off) ? part[tid - off] : 0;
        __syncthreads();
        part[tid] = v + add;
        __syncthreads();
    }
    int pos = part[tid] - local;  // exclusive prefix
    #pragma unroll
    for (int j = 0; j < 8; j++) {
        int t = base + j;
        if (f[j]) {
            int s0 = si[t * 4 + 0], s1 = si[t * 4 + 1];
            int s2 = si[t * 4 + 2], s3 = si[t * 4 + 3];
            sel_tok[pos] = t;
            packed[pos] = (unsigned)s0 | ((unsigned)s1 << 8) |
                          ((unsigned)s2 << 16) | ((unsigned)s3 << 24);
            pos++;
            atomicAdd(&s_counts[s0], 1);
            if (s1 != s0) atomicAdd(&s_counts[s1], 1);
            if (s2 != s0 && s2 != s1) atomicAdd(&s_counts[s2], 1);
            if (s3 != s0 && s3 != s1 && s3 != s2) atomicAdd(&s_counts[s3], 1);
        }
    }
    __syncthreads();
    if (tid < NSLOT) counts[tid] = s_counts[tid];
}

// ---------------- Kernel 4: segment-mean + EMA + write full output ----------------
__global__ __launch_bounds__(256) void update_kernel(
    const float* __restrict__ h, const float* __restrict__ mem,
    const int* __restrict__ sel_tok, const unsigned int* __restrict__ packed,
    const int* __restrict__ counts, float* __restrict__ out)
{
    const int slot = blockIdx.x >> 2;   // 128 slots
    const int chunk = blockIdx.x & 3;   // 4 chunks of 1024 floats
    __shared__ unsigned int s_packed[TOPK];
    __shared__ int s_tok[TOPK];
    for (int i = threadIdx.x; i < TOPK; i += 256) {
        s_packed[i] = packed[i];
        s_tok[i] = sel_tok[i];
    }
    __syncthreads();
    const unsigned pat = (unsigned)slot * 0x01010101u;
    float4 acc = make_float4(0.f, 0.f, 0.f, 0.f);
    const int dbase = chunk * 1024 + threadIdx.x * 4;
    for (int i = 0; i < TOPK; i++) {
        unsigned p = s_packed[i] ^ pat;
        // any byte == 0  <=>  slot appears in this token's retrieved set
        bool member = ((p - 0x01010101u) & ~p & 0x80808080u) != 0u;
        if (member) {
            const float4 x = *reinterpret_cast<const float4*>(
                h + (size_t)s_tok[i] * HDIM + dbase);
            acc.x += x.x; acc.y += x.y; acc.z += x.z; acc.w += x.w;
        }
    }
    const int cnt = counts[slot];
    const size_t o = (size_t)slot * HDIM + dbase;
    float4 cur = *reinterpret_cast<const float4*>(mem + o);
    float4 r;
    if (cnt > 0) {
        float inv = 1.0f / (float)cnt;
        r.x = ALPHA * (acc.x * inv) + (1.f - ALPHA) * cur.x;
        r.y = ALPHA * (acc.y * inv) + (1.f - ALPHA) * cur.y;
        r.z = ALPHA * (acc.z * inv) + (1.f - ALPHA) * cur.z;
        r.w = ALPHA * (acc.w * inv) + (1.f - ALPHA) * cur.w;
    } else {
        r = cur;
    }
    *reinterpret_cast<float4*>(out + o) = r;
}

extern "C" void kernel_launch(void* const* d_in, const int* in_sizes, int n_in,
                              void* d_out, int out_size, void* d_ws, size_t ws_size,
                              hipStream_t stream) {
    const float* h    = (const float*)d_in[0];  // [8192, 4096]
    const float* attn = (const float*)d_in[1];  // [8192, 4]
    const int*   si   = (const int*)d_in[2];    // [8192, 4]
    const float* mem  = (const float*)d_in[3];  // [1, 128, 4096]
    const float* W    = (const float*)d_in[4];  // [1, 4096]
    const float* b    = (const float*)d_in[5];  // [1]
    float* out = (float*)d_out;                 // [1, 128, 4096]

    char* ws = (char*)d_ws;
    float*        imp     = (float*)(ws);                 // 8192 f32
    int*          rank    = (int*)(ws + 32768);           // 8192 i32
    int*          sel_tok = (int*)(ws + 65536);           // 2048 i32
    unsigned int* packed  = (unsigned int*)(ws + 73728);  // 2048 u32
    int*          counts  = (int*)(ws + 81920);           // 128 i32

    importance_kernel<<<T_TOK, 256, 0, stream>>>(h, attn, W, b, imp, rank);
    rank_kernel<<<1024, 256, 0, stream>>>(imp, rank);
    compact_kernel<<<1, 1024, 0, stream>>>(rank, si, sel_tok, packed, counts);
    update_kernel<<<NSLOT * 4, 256, 0, stream>>>(h, mem, sel_tok, packed, counts, out);
}

// Round 3
// 61.167 us; speedup vs baseline: 5.9609x; 2.9479x over previous
//
#include <hip/hip_runtime.h>
#include <math.h>

#define T_TOK 8192
#define HDIM 4096
#define NSLOT 128
#define KRET 4
#define TOPK 2048
#define ALPHA 0.1f
#define MAXC 2048   // hard bound: a slot appears at most once per selected token

// ---------------- Kernel 1: per-token importance (+ zero rank) ----------------
__global__ __launch_bounds__(256) void importance_kernel(
    const float* __restrict__ h, const float* __restrict__ attn,
    const float* __restrict__ W, const float* __restrict__ b,
    float* __restrict__ imp, int* __restrict__ rank)
{
    const int t = blockIdx.x;
    const float4* hv = reinterpret_cast<const float4*>(h + (size_t)t * HDIM);
    const float4* Wv = reinterpret_cast<const float4*>(W);
    float sumsq = 0.f, dot = 0.f;
    for (int i = threadIdx.x; i < HDIM / 4; i += 256) {
        float4 x = hv[i];
        float4 w = Wv[i];
        sumsq += x.x * x.x + x.y * x.y + x.z * x.z + x.w * x.w;
        dot   += x.x * w.x + x.y * w.y + x.z * w.z + x.w * w.w;
    }
    #pragma unroll
    for (int off = 32; off > 0; off >>= 1) {
        sumsq += __shfl_down(sumsq, off);
        dot   += __shfl_down(dot, off);
    }
    __shared__ float s_sq[4], s_dot[4];
    const int lane = threadIdx.x & 63, wid = threadIdx.x >> 6;
    if (lane == 0) { s_sq[wid] = sumsq; s_dot[wid] = dot; }
    __syncthreads();
    if (threadIdx.x == 0) {
        float sq = s_sq[0] + s_sq[1] + s_sq[2] + s_sq[3];
        float dt = s_dot[0] + s_dot[1] + s_dot[2] + s_dot[3];
        float mag = sqrtf(sq);
        float ent = 0.f;
        #pragma unroll
        for (int k = 0; k < KRET; k++) {
            float a = attn[t * KRET + k];
            ent -= a * logf(a + 1e-8f);
        }
        float surprise = ent / logf(4.0f);
        float score = dt + b[0];
        float sig = 1.0f / (1.0f + expf(-score));
        imp[t] = mag * (1.0f + surprise) + sig;
        rank[t] = 0;  // zero for rank_kernel (stream-ordered, replay-safe)
    }
}

// ---------------- Kernel 2: partial rank count, 2-D grid ----------------
__global__ __launch_bounds__(256) void rank_kernel(
    const float* __restrict__ imp, int* __restrict__ rank)
{
    const int cb = blockIdx.x & 31;   // candidate block
    const int sl = blockIdx.x >> 5;   // compare slice
    __shared__ float tile[256];
    const int base = sl * 256;
    tile[threadIdx.x] = imp[base + threadIdx.x];
    __syncthreads();
    const int t = cb * 256 + threadIdx.x;
    const float mine = imp[t];
    int r = 0;
    #pragma unroll 8
    for (int i = 0; i < 256; i++) {
        float v = tile[i];
        int s = base + i;
        // jax.lax.top_k tie-break: higher value first, then lower index
        r += (v > mine) || (v == mine && s < t);
    }
    if (r) atomicAdd(&rank[t], r);
}

// ---------------- Kernel 3: ordered compaction of selected tokens ----------------
__global__ __launch_bounds__(1024) void compact_kernel(
    const int* __restrict__ rank, const int* __restrict__ si,
    int* __restrict__ sel_tok, unsigned int* __restrict__ packed)
{
    __shared__ int part[1024];
    const int tid = threadIdx.x;
    const int base = tid * 8;
    int f[8];
    int local = 0;
    #pragma unroll
    for (int j = 0; j < 8; j++) {
        f[j] = (rank[base + j] < TOPK) ? 1 : 0;
        local += f[j];
    }
    part[tid] = local;
    __syncthreads();
    for (int off = 1; off < 1024; off <<= 1) {
        int v = part[tid];
        int add = (tid >= off) ? part[tid - off] : 0;
        __syncthreads();
        part[tid] = v + add;
        __syncthreads();
    }
    int pos = part[tid] - local;  // exclusive prefix
    #pragma unroll
    for (int j = 0; j < 8; j++) {
        int t = base + j;
        if (f[j]) {
            int s0 = si[t * 4 + 0], s1 = si[t * 4 + 1];
            int s2 = si[t * 4 + 2], s3 = si[t * 4 + 3];
            sel_tok[pos] = t;
            packed[pos] = (unsigned)s0 | ((unsigned)s1 << 8) |
                          ((unsigned)s2 << 16) | ((unsigned)s3 << 24);
            pos++;
        }
    }
}

// ---------------- Kernel 3b: per-slot CSR list (deterministic, ordered) -------
// One block per slot; ordered compaction of member tokens via LDS scan.
__global__ __launch_bounds__(256) void slotlist_kernel(
    const int* __restrict__ sel_tok, const unsigned int* __restrict__ packed,
    int* __restrict__ lists, int* __restrict__ counts)
{
    const int slot = blockIdx.x;
    const unsigned pat = (unsigned)slot * 0x01010101u;
    const int tid = threadIdx.x;
    __shared__ int part[256];
    const int base = tid * 8;
    int f[8];
    int local = 0;
    #pragma unroll
    for (int j = 0; j < 8; j++) {
        unsigned p = packed[base + j] ^ pat;
        f[j] = (((p - 0x01010101u) & ~p & 0x80808080u) != 0u) ? 1 : 0;
        local += f[j];
    }
    part[tid] = local;
    __syncthreads();
    for (int off = 1; off < 256; off <<= 1) {
        int v = part[tid];
        int add = (tid >= off) ? part[tid - off] : 0;
        __syncthreads();
        part[tid] = v + add;
        __syncthreads();
    }
    int pos = part[tid] - local;  // exclusive prefix
    int* mylist = lists + (size_t)slot * MAXC;
    #pragma unroll
    for (int j = 0; j < 8; j++) {
        if (f[j]) mylist[pos++] = sel_tok[base + j];
    }
    if (tid == 255) counts[slot] = part[255];
}

// ---------------- Kernel 4: CSR gather + segment-mean + EMA ----------------
__global__ __launch_bounds__(256) void update_kernel(
    const float* __restrict__ h, const float* __restrict__ mem,
    const int* __restrict__ lists, const int* __restrict__ counts,
    float* __restrict__ out)
{
    const int slot = blockIdx.x >> 2;   // 128 slots
    const int chunk = blockIdx.x & 3;   // 4 chunks of 1024 floats
    const int cnt = counts[slot];
    __shared__ int s_list[MAXC];
    for (int i = threadIdx.x; i < cnt; i += 256)
        s_list[i] = lists[(size_t)slot * MAXC + i];
    __syncthreads();

    const int dbase = chunk * 1024 + threadIdx.x * 4;
    float4 acc = make_float4(0.f, 0.f, 0.f, 0.f);
    int i = 0;
    for (; i + 4 <= cnt; i += 4) {
        int t0 = s_list[i], t1 = s_list[i + 1];
        int t2 = s_list[i + 2], t3 = s_list[i + 3];
        float4 x0 = *reinterpret_cast<const float4*>(h + (size_t)t0 * HDIM + dbase);
        float4 x1 = *reinterpret_cast<const float4*>(h + (size_t)t1 * HDIM + dbase);
        float4 x2 = *reinterpret_cast<const float4*>(h + (size_t)t2 * HDIM + dbase);
        float4 x3 = *reinterpret_cast<const float4*>(h + (size_t)t3 * HDIM + dbase);
        acc.x += x0.x + x1.x + x2.x + x3.x;
        acc.y += x0.y + x1.y + x2.y + x3.y;
        acc.z += x0.z + x1.z + x2.z + x3.z;
        acc.w += x0.w + x1.w + x2.w + x3.w;
    }
    for (; i < cnt; i++) {
        int t0 = s_list[i];
        float4 x0 = *reinterpret_cast<const float4*>(h + (size_t)t0 * HDIM + dbase);
        acc.x += x0.x; acc.y += x0.y; acc.z += x0.z; acc.w += x0.w;
    }

    const size_t o = (size_t)slot * HDIM + dbase;
    float4 cur = *reinterpret_cast<const float4*>(mem + o);
    float4 r;
    if (cnt > 0) {
        float inv = 1.0f / (float)cnt;
        r.x = ALPHA * (acc.x * inv) + (1.f - ALPHA) * cur.x;
        r.y = ALPHA * (acc.y * inv) + (1.f - ALPHA) * cur.y;
        r.z = ALPHA * (acc.z * inv) + (1.f - ALPHA) * cur.z;
        r.w = ALPHA * (acc.w * inv) + (1.f - ALPHA) * cur.w;
    } else {
        r = cur;
    }
    *reinterpret_cast<float4*>(out + o) = r;
}

extern "C" void kernel_launch(void* const* d_in, const int* in_sizes, int n_in,
                              void* d_out, int out_size, void* d_ws, size_t ws_size,
                              hipStream_t stream) {
    const float* h    = (const float*)d_in[0];  // [8192, 4096]
    const float* attn = (const float*)d_in[1];  // [8192, 4]
    const int*   si   = (const int*)d_in[2];    // [8192, 4]
    const float* mem  = (const float*)d_in[3];  // [1, 128, 4096]
    const float* W    = (const float*)d_in[4];  // [1, 4096]
    const float* b    = (const float*)d_in[5];  // [1]
    float* out = (float*)d_out;                 // [1, 128, 4096]

    char* ws = (char*)d_ws;
    float*        imp     = (float*)(ws);                 // 8192 f32
    int*          rank    = (int*)(ws + 32768);           // 8192 i32
    int*          sel_tok = (int*)(ws + 65536);           // 2048 i32
    unsigned int* packed  = (unsigned int*)(ws + 73728);  // 2048 u32
    int*          counts  = (int*)(ws + 81920);           // 128 i32
    int*          lists   = (int*)(ws + 131072);          // 128 x 2048 i32 (1 MB)

    importance_kernel<<<T_TOK, 256, 0, stream>>>(h, attn, W, b, imp, rank);
    rank_kernel<<<1024, 256, 0, stream>>>(imp, rank);
    compact_kernel<<<1, 1024, 0, stream>>>(rank, si, sel_tok, packed);
    slotlist_kernel<<<NSLOT, 256, 0, stream>>>(sel_tok, packed, lists, counts);
    update_kernel<<<NSLOT * 4, 256, 0, stream>>>(h, mem, lists, counts, out);
}

// Round 4
// 59.944 us; speedup vs baseline: 6.0826x; 1.0204x over previous
//
#include <hip/hip_runtime.h>
#include <math.h>

#define T_TOK 8192
#define HDIM 4096
#define NSLOT 128
#define KRET 4
#define TOPK 2048
#define ALPHA 0.1f
#define MAXC 2048   // hard bound: a slot appears at most once per selected token

// ---------------- Kernel 1: per-token importance, one wave per token ----------
__global__ __launch_bounds__(256) void importance_kernel(
    const float* __restrict__ h, const float* __restrict__ attn,
    const float* __restrict__ W, const float* __restrict__ b,
    float* __restrict__ imp, int* __restrict__ rank)
{
    const int wid  = threadIdx.x >> 6;
    const int lane = threadIdx.x & 63;
    const int t = blockIdx.x * 4 + wid;
    const float4* hv = reinterpret_cast<const float4*>(h + (size_t)t * HDIM);
    const float4* Wv = reinterpret_cast<const float4*>(W);
    float sumsq = 0.f, dot = 0.f;
    #pragma unroll 4
    for (int i = 0; i < 16; i++) {
        float4 x = hv[lane + i * 64];
        float4 w = Wv[lane + i * 64];
        sumsq += x.x * x.x + x.y * x.y + x.z * x.z + x.w * x.w;
        dot   += x.x * w.x + x.y * w.y + x.z * w.z + x.w * w.w;
    }
    #pragma unroll
    for (int off = 32; off > 0; off >>= 1) {
        sumsq += __shfl_down(sumsq, off);
        dot   += __shfl_down(dot, off);
    }
    if (lane == 0) {
        float mag = sqrtf(sumsq);
        float ent = 0.f;
        #pragma unroll
        for (int k = 0; k < KRET; k++) {
            float a = attn[t * KRET + k];
            ent -= a * logf(a + 1e-8f);
        }
        float surprise = ent / logf(4.0f);
        float score = dot + b[0];
        float sig = 1.0f / (1.0f + expf(-score));
        imp[t] = mag * (1.0f + surprise) + sig;
        rank[t] = 0;  // zero for rank_kernel (stream-ordered, replay-safe)
    }
}

// ---------------- Kernel 2: partial rank count, 2-D grid ----------------
__global__ __launch_bounds__(256) void rank_kernel(
    const float* __restrict__ imp, int* __restrict__ rank)
{
    const int cb = blockIdx.x & 31;   // candidate block
    const int sl = blockIdx.x >> 5;   // compare slice
    __shared__ float tile[256];
    const int base = sl * 256;
    tile[threadIdx.x] = imp[base + threadIdx.x];
    __syncthreads();
    const int t = cb * 256 + threadIdx.x;
    const float mine = imp[t];
    int r = 0;
    #pragma unroll 8
    for (int i = 0; i < 256; i++) {
        float v = tile[i];
        int s = base + i;
        // jax.lax.top_k tie-break: higher value first, then lower index
        r += (v > mine) || (v == mine && s < t);
    }
    if (r) atomicAdd(&rank[t], r);
}

// ---------------- Kernel 3: per-slot CSR list, direct from rank+si ----------
// One block per slot; ordered compaction (ascending t) -> deterministic.
__global__ __launch_bounds__(256) void slotlist_kernel(
    const int* __restrict__ rank, const int* __restrict__ si,
    int* __restrict__ lists, int* __restrict__ counts)
{
    const int slot = blockIdx.x;
    const int tid = threadIdx.x;
    __shared__ int part[256];
    const int base = tid * 32;
    unsigned mask = 0;
    int local = 0;
    const int4* si4 = reinterpret_cast<const int4*>(si);
    #pragma unroll 8
    for (int j = 0; j < 32; j++) {
        const int t = base + j;
        int4 s = si4[t];
        bool sel = rank[t] < TOPK;
        bool mem = (s.x == slot) | (s.y == slot) | (s.z == slot) | (s.w == slot);
        if (sel && mem) { mask |= (1u << j); local++; }
    }
    part[tid] = local;
    __syncthreads();
    for (int off = 1; off < 256; off <<= 1) {
        int v = part[tid];
        int add = (tid >= off) ? part[tid - off] : 0;
        __syncthreads();
        part[tid] = v + add;
        __syncthreads();
    }
    int pos = part[tid] - local;  // exclusive prefix
    int* mylist = lists + (size_t)slot * MAXC;
    for (int j = 0; j < 32; j++) {
        if (mask & (1u << j)) mylist[pos++] = base + j;
    }
    if (tid == 255) counts[slot] = part[255];
}

// ---------------- Kernel 4: CSR gather + segment-mean + EMA ----------------
__global__ __launch_bounds__(256) void update_kernel(
    const float* __restrict__ h, const float* __restrict__ mem,
    const int* __restrict__ lists, const int* __restrict__ counts,
    float* __restrict__ out)
{
    const int slot = blockIdx.x >> 2;   // 128 slots
    const int chunk = blockIdx.x & 3;   // 4 chunks of 1024 floats
    const int cnt = counts[slot];
    __shared__ int s_list[MAXC];
    for (int i = threadIdx.x; i < cnt; i += 256)
        s_list[i] = lists[(size_t)slot * MAXC + i];
    __syncthreads();

    const int dbase = chunk * 1024 + threadIdx.x * 4;
    float4 acc = make_float4(0.f, 0.f, 0.f, 0.f);
    int i = 0;
    for (; i + 4 <= cnt; i += 4) {
        int t0 = s_list[i], t1 = s_list[i + 1];
        int t2 = s_list[i + 2], t3 = s_list[i + 3];
        float4 x0 = *reinterpret_cast<const float4*>(h + (size_t)t0 * HDIM + dbase);
        float4 x1 = *reinterpret_cast<const float4*>(h + (size_t)t1 * HDIM + dbase);
        float4 x2 = *reinterpret_cast<const float4*>(h + (size_t)t2 * HDIM + dbase);
        float4 x3 = *reinterpret_cast<const float4*>(h + (size_t)t3 * HDIM + dbase);
        acc.x += x0.x + x1.x + x2.x + x3.x;
        acc.y += x0.y + x1.y + x2.y + x3.y;
        acc.z += x0.z + x1.z + x2.z + x3.z;
        acc.w += x0.w + x1.w + x2.w + x3.w;
    }
    for (; i < cnt; i++) {
        int t0 = s_list[i];
        float4 x0 = *reinterpret_cast<const float4*>(h + (size_t)t0 * HDIM + dbase);
        acc.x += x0.x; acc.y += x0.y; acc.z += x0.z; acc.w += x0.w;
    }

    const size_t o = (size_t)slot * HDIM + dbase;
    float4 cur = *reinterpret_cast<const float4*>(mem + o);
    float4 r;
    if (cnt > 0) {
        float inv = 1.0f / (float)cnt;
        r.x = ALPHA * (acc.x * inv) + (1.f - ALPHA) * cur.x;
        r.y = ALPHA * (acc.y * inv) + (1.f - ALPHA) * cur.y;
        r.z = ALPHA * (acc.z * inv) + (1.f - ALPHA) * cur.z;
        r.w = ALPHA * (acc.w * inv) + (1.f - ALPHA) * cur.w;
    } else {
        r = cur;
    }
    *reinterpret_cast<float4*>(out + o) = r;
}

extern "C" void kernel_launch(void* const* d_in, const int* in_sizes, int n_in,
                              void* d_out, int out_size, void* d_ws, size_t ws_size,
                              hipStream_t stream) {
    const float* h    = (const float*)d_in[0];  // [8192, 4096]
    const float* attn = (const float*)d_in[1];  // [8192, 4]
    const int*   si   = (const int*)d_in[2];    // [8192, 4]
    const float* mem  = (const float*)d_in[3];  // [1, 128, 4096]
    const float* W    = (const float*)d_in[4];  // [1, 4096]
    const float* b    = (const float*)d_in[5];  // [1]
    float* out = (float*)d_out;                 // [1, 128, 4096]

    char* ws = (char*)d_ws;
    float* imp    = (float*)(ws);            // 8192 f32
    int*   rank   = (int*)(ws + 32768);      // 8192 i32
    int*   counts = (int*)(ws + 65536);      // 128 i32
    int*   lists  = (int*)(ws + 131072);     // 128 x 2048 i32 (1 MB)

    importance_kernel<<<T_TOK / 4, 256, 0, stream>>>(h, attn, W, b, imp, rank);
    rank_kernel<<<1024, 256, 0, stream>>>(imp, rank);
    slotlist_kernel<<<NSLOT, 256, 0, stream>>>(rank, si, lists, counts);
    update_kernel<<<NSLOT * 4, 256, 0, stream>>>(h, mem, lists, counts, out);
}